// Round 8
// baseline (130.529 us; speedup 1.0000x reference)
//
#include <hip/hip_runtime.h>
#include <hip/hip_bf16.h>

// Fused: qp=QWq^T+bq etc, then O = Qp (Kp^T Vp) (no softmax -> associativity),
// out[b,c,h,w] = O[w][c] + q[b,c,h,w].  bf16 MFMA, fp32 accum.
// Round 8: R5 verbatim (53KB LDS, 3 blocks/CU, one-shot 4096 natural order)
// EXCEPT P4 now uses mfma_32x32x16 so each wave writes COMPLETE 128-B output
// lines (4 back-to-back dwordx4 per line, single wave) -- tests the theory
// that R5's traffic blowup was L2 partial-line eviction (RFO + double-write)
// from the old 2-wave/8-chunk line assembly. One barrier added (sQP is now
// consumed cross-wave).

typedef __bf16 bf16x8 __attribute__((ext_vector_type(8)));
typedef float  f32x4  __attribute__((ext_vector_type(4)));
typedef float  f32x16 __attribute__((ext_vector_type(16)));

#define LDP 68    // row stride (bf16 elems): 136B rows, 8B-aligned

// LDS regions (ushort offsets), each [64][LDP] = 4352
#define OF_KS 0        // Kstage (half)   } sQ [128][68] later
#define OF_VS 4352     // Vstage (half)   }
#define OF_KP 8704     // Kp^T_h          } sQP [128][68] later
#define OF_VP 13056    // Vp^T_h          }
#define OF_TT 17408    // Tt [64][68]
#define OF_WQ 21760    // Wq [64][68]
#define OF_SB 26112    // float sB[192]: [0:64)=bq [64:128)=bk [128:192)=bv
#define LDS_USHORTS (26112 + 384)

// XOR swizzle (16B granule, key = row bits 2..4) for staged-input buffers only
#define SWZ(row, col) ((col) ^ ((((row) >> 2) & 7) << 3))

__device__ __forceinline__ unsigned short f2bf(float x) {
  __hip_bfloat16 h = __float2bfloat16(x);           // RNE
  return __builtin_bit_cast(unsigned short, h);
}
__device__ __forceinline__ float bf2f(unsigned short u) {
  unsigned int t = ((unsigned int)u) << 16;
  return __builtin_bit_cast(float, t);
}
__device__ __forceinline__ unsigned int pack2(float a, float b) {
  return (unsigned int)f2bf(a) | ((unsigned int)f2bf(b) << 16);
}
__device__ __forceinline__ bf16x8 cvt8(float4 a, float4 b) {
  union { unsigned int u[4]; bf16x8 v; } r;
  r.u[0] = pack2(a.x, a.y); r.u[1] = pack2(a.z, a.w);
  r.u[2] = pack2(b.x, b.y); r.u[3] = pack2(b.z, b.w);
  return r.v;
}
// load 8 contiguous bf16 (8B-aligned) as an MFMA fragment
__device__ __forceinline__ bf16x8 ld8(const unsigned short* p) {
  uint2 lo = *reinterpret_cast<const uint2*>(p);
  uint2 hi = *reinterpret_cast<const uint2*>(p + 4);
  uint4 t;
  t.x = lo.x; t.y = lo.y; t.z = hi.x; t.w = hi.y;
  return __builtin_bit_cast(bf16x8, t);
}

__global__ __launch_bounds__(512, 6)
void fused_mha(const float* __restrict__ q, const float* __restrict__ k,
               const float* __restrict__ v,
               const float* __restrict__ wq, const float* __restrict__ bq,
               const float* __restrict__ wk, const float* __restrict__ bk,
               const float* __restrict__ wv, const float* __restrict__ bv,
               float* __restrict__ out)
{
  __shared__ __align__(16) unsigned short lds[LDS_USHORTS];
  unsigned short* sKS = lds + OF_KS;   // stage K half [64][LDP] (SWZ)
  unsigned short* sVS = lds + OF_VS;   // stage V half (SWZ)
  unsigned short* sKP = lds + OF_KP;   // Kp^T_h [o][xl] plain
  unsigned short* sVP = lds + OF_VP;   // Vp^T_h plain
  unsigned short* sTt = lds + OF_TT;   // Tt[c][d] plain
  unsigned short* sWq = lds + OF_WQ;   // Wq [o][c] plain
  unsigned short* sQ  = lds + OF_KS;   // q [128][LDP] (SWZ), over KS+VS
  unsigned short* sQP = lds + OF_KP;   // Qp [128][LDP] plain, over KP+VP
  float* sB = (float*)(lds + OF_SB);

  const int tid  = threadIdx.x;
  const int lane = tid & 63;
  const int ww   = tid >> 6;     // wave 0..7
  const int l15  = lane & 15;
  const int g    = lane >> 4;    // 0..3

  const size_t CS = 128*128;
  const int bh = blockIdx.x;
  const size_t base = (size_t)(bh >> 7)*(64*CS) + (size_t)(bh & 127)*128;

  // staging mapping: 4 consecutive rows (within a half), 2 channels, 2 halves
  const int sw0 = 4*(tid & 15);            // rows sw0..sw0+3 (half-local)
  const int scA = 2*((tid >> 4) & 31);     // channel pair
  const int swk = ((tid & 15) & 7) << 3;   // = ((row>>2)&7)<<3 for those rows

  // ---------------- prologue ----------------
  // k/v loads first (HBM latency starts now): [half][channel e]
  float4 kreg[4], vreg[4];
  #pragma unroll
  for (int h = 0; h < 2; ++h)
    #pragma unroll
    for (int e = 0; e < 2; ++e) {
      kreg[2*h+e] = *(const float4*)(k + base + (size_t)(scA+e)*CS + sw0 + 64*h);
      vreg[2*h+e] = *(const float4*)(v + base + (size_t)(scA+e)*CS + sw0 + 64*h);
    }
  // weight fragments for K/V projections (wave's o-tile rt)
  const int rt = ww & 3;
  const int xb = (ww >> 2) * 2;            // x-tiles xb, xb+1 within a half
  bf16x8 wkf[2], wvf[2];
  #pragma unroll
  for (int ks = 0; ks < 2; ++ks) {
    const float* pk = wk + (16*rt + l15)*64 + 8*g + 32*ks;
    const float* pv = wv + (16*rt + l15)*64 + 8*g + 32*ks;
    wkf[ks] = cvt8(*(const float4*)pk, *(const float4*)(pk+4));
    wvf[ks] = cvt8(*(const float4*)pv, *(const float4*)(pv+4));
  }
  // Wq -> LDS (plain)
  {
    const int o  = tid >> 3;
    const int c0 = (tid & 7) * 8;
    float4 a = *(const float4*)(wq + o*64 + c0);
    float4 b = *(const float4*)(wq + o*64 + c0 + 4);
    unsigned short* p = &sWq[o*LDP + c0];
    ((uint2*)p)[0] = make_uint2(pack2(a.x,a.y), pack2(a.z,a.w));
    ((uint2*)p)[1] = make_uint2(pack2(b.x,b.y), pack2(b.z,b.w));
  }
  if (tid < 64)        sB[tid] = bq[tid];
  else if (tid < 128)  sB[tid] = bk[tid-64];
  else if (tid < 192)  sB[tid] = bv[tid-128];

  // ---------------- PW0: drain k/v half 0 ----------------
  {
    const int c = scA ^ swk;
    const float* ka = (const float*)&kreg[0];
    const float* kb = (const float*)&kreg[1];
    const float* va = (const float*)&vreg[0];
    const float* vb = (const float*)&vreg[1];
    #pragma unroll
    for (int j = 0; j < 4; ++j) {
      *(unsigned int*)&sKS[(sw0+j)*LDP + c] = pack2(ka[j], kb[j]);
      *(unsigned int*)&sVS[(sw0+j)*LDP + c] = pack2(va[j], vb[j]);
    }
  }
  __syncthreads();                                   // B1

  f32x4 z = {0.f,0.f,0.f,0.f};
  f32x4 tacc[2] = {z, z};                            // T accumulator (both halves)
  const int rt2 = ww >> 1;
  const int cb2 = (ww & 1) * 2;
  float4 qreg[4];

  #pragma unroll
  for (int h = 0; h < 2; ++h) {
    // ---------- P1h: Kp^T_h[o][xl], Vp^T_h[o][xl] ----------
    {
      f32x4 acck[2] = {z,z}, accv[2] = {z,z};
      #pragma unroll
      for (int ks = 0; ks < 2; ++ks) {
        #pragma unroll
        for (int cc = 0; cc < 2; ++cc) {
          int row = 16*(xb+cc) + l15;
          int col = SWZ(row, 32*ks + 8*g);
          bf16x8 bk8 = ld8(&sKS[row*LDP + col]);
          bf16x8 bv8 = ld8(&sVS[row*LDP + col]);
          acck[cc] = __builtin_amdgcn_mfma_f32_16x16x32_bf16(wkf[ks], bk8, acck[cc], 0, 0, 0);
          accv[cc] = __builtin_amdgcn_mfma_f32_16x16x32_bf16(wvf[ks], bv8, accv[cc], 0, 0, 0);
        }
      }
      #pragma unroll
      for (int cc = 0; cc < 2; ++cc) {
        int xl = 16*(xb+cc) + l15;
        #pragma unroll
        for (int r = 0; r < 4; ++r) {
          int o = 16*rt + 4*g + r;
          sKP[o*LDP + xl] = f2bf(acck[cc][r] + sB[64 + o]);
          sVP[o*LDP + xl] = f2bf(accv[cc][r] + sB[128 + o]);
        }
      }
    }
    __syncthreads();                                 // B2 / B4

    // ---------- P2h: Tt += ; plus PW1 (h=0) or q-drain (h=1) ----------
    if (h == 0) {
      // drain k/v half 1 into stage (P1h0's reads are behind B2)
      const int c = scA ^ swk;
      const float* ka = (const float*)&kreg[2];
      const float* kb = (const float*)&kreg[3];
      const float* va = (const float*)&vreg[2];
      const float* vb = (const float*)&vreg[3];
      #pragma unroll
      for (int j = 0; j < 4; ++j) {
        *(unsigned int*)&sKS[(sw0+j)*LDP + c] = pack2(ka[j], kb[j]);
        *(unsigned int*)&sVS[(sw0+j)*LDP + c] = pack2(va[j], vb[j]);
      }
      // issue q loads now (consumed next phase; k/v regs just died)
      #pragma unroll
      for (int hh = 0; hh < 2; ++hh)
        #pragma unroll
        for (int e = 0; e < 2; ++e)
          qreg[2*hh+e] = *(const float4*)(q + base + (size_t)(scA+e)*CS + sw0 + 64*hh);
    } else {
      // drain q -> sQ (stage region; P1h1's reads are behind B4)
      #pragma unroll
      for (int hh = 0; hh < 2; ++hh) {
        const int c = scA ^ swk;
        const float* qa = (const float*)&qreg[2*hh];
        const float* qb = (const float*)&qreg[2*hh+1];
        #pragma unroll
        for (int j = 0; j < 4; ++j)
          *(unsigned int*)&sQ[(sw0 + 64*hh + j)*LDP + c] = pack2(qa[j], qb[j]);
      }
    }
    {
      #pragma unroll
      for (int ks = 0; ks < 2; ++ks) {
        int arow = 16*rt2 + l15;
        bf16x8 a = ld8(&sVP[arow*LDP + 32*ks + 8*g]);
        #pragma unroll
        for (int cc = 0; cc < 2; ++cc) {
          int brow = 16*(cb2+cc) + l15;
          bf16x8 b = ld8(&sKP[brow*LDP + 32*ks + 8*g]);
          tacc[cc] = __builtin_amdgcn_mfma_f32_16x16x32_bf16(a, b, tacc[cc], 0, 0, 0);
        }
      }
    }
    if (h == 1) {
      // write Tt (both halves accumulated)
      #pragma unroll
      for (int cc = 0; cc < 2; ++cc) {
        int d = 16*(cb2+cc) + l15;
        #pragma unroll
        for (int r = 0; r < 4; ++r)
          sTt[(16*rt2 + 4*g + r)*LDP + d] = f2bf(tacc[cc][r]);
      }
    }
    __syncthreads();                                 // B3 / B5
  }

  // ---------- P3: Qp[w][o] -> sQP (over dead KPt/VPt) ----------
  {
    f32x4 acc[4] = {z,z,z,z};
    #pragma unroll
    for (int ks = 0; ks < 2; ++ks) {
      int arow = 16*ww + l15;
      bf16x8 a = ld8(&sQ[arow*LDP + SWZ(arow, 32*ks + 8*g)]);
      #pragma unroll
      for (int ct = 0; ct < 4; ++ct) {
        bf16x8 b = ld8(&sWq[(16*ct + l15)*LDP + 32*ks + 8*g]);
        acc[ct] = __builtin_amdgcn_mfma_f32_16x16x32_bf16(a, b, acc[ct], 0, 0, 0);
      }
    }
    #pragma unroll
    for (int ct = 0; ct < 4; ++ct) {
      float bias = sB[16*ct + l15];
      #pragma unroll
      for (int r = 0; r < 4; ++r)
        sQP[(16*ww + 4*g + r)*LDP + 16*ct + l15] = f2bf(acc[ct][r] + bias);
    }
  }
  __syncthreads();                                   // B6: sQP now cross-wave

  // ---------- P4 (32x32): O[w][c'] = Qp·Tt^T; whole-line stores ----------
  // Wave ww owns O-tile [32*(ww&3) .. +32) x [32*(ww>>2) .. +32).
  // D layout (m74/m101): col = lane&31, row = (reg&3) + 8*(reg>>2) + 4*(lane>>5).
  {
    const int l31 = lane & 31;
    const int lh  = lane >> 5;           // 0/1
    const int wt  = ww & 3;              // w-tile
    const int ct2 = ww >> 2;             // c'-tile
    f32x16 acc16 = {};
    #pragma unroll
    for (int ks = 0; ks < 4; ++ks) {     // K = 64, 16 per mfma
      bf16x8 a = ld8(&sQP[(32*wt + l31)*LDP + 16*ks + 8*lh]);
      bf16x8 b = ld8(&sTt[(32*ct2 + l31)*LDP + 16*ks + 8*lh]);
      acc16 = __builtin_amdgcn_mfma_f32_32x32x16_bf16(a, b, acc16, 0, 0, 0);
    }
    const int cg = 32*ct2 + l31;         // global output channel
    #pragma unroll
    for (int jg = 0; jg < 4; ++jg) {     // rows 8*jg + 4*lh + 0..3
      int w0 = 32*wt + 8*jg + 4*lh;
      float4 o4;
      o4.x = acc16[4*jg+0] + bf2f(sQ[(w0+0)*LDP + SWZ(w0+0, cg)]);
      o4.y = acc16[4*jg+1] + bf2f(sQ[(w0+1)*LDP + SWZ(w0+1, cg)]);
      o4.z = acc16[4*jg+2] + bf2f(sQ[(w0+2)*LDP + SWZ(w0+2, cg)]);
      o4.w = acc16[4*jg+3] + bf2f(sQ[(w0+3)*LDP + SWZ(w0+3, cg)]);
      *reinterpret_cast<float4*>(out + base + (size_t)cg * CS + w0) = o4;
    }
  }
}

extern "C" void kernel_launch(void* const* d_in, const int* in_sizes, int n_in,
                              void* d_out, int out_size, void* d_ws, size_t ws_size,
                              hipStream_t stream) {
  (void)in_sizes; (void)n_in; (void)d_ws; (void)ws_size; (void)out_size;
  const float* q  = (const float*)d_in[0];
  const float* k  = (const float*)d_in[1];
  const float* v  = (const float*)d_in[2];
  const float* wq = (const float*)d_in[3];
  const float* bq = (const float*)d_in[4];
  const float* wk = (const float*)d_in[5];
  const float* bk = (const float*)d_in[6];
  const float* wv = (const float*)d_in[7];
  const float* bv = (const float*)d_in[8];
  float* out = (float*)d_out;
  fused_mha<<<dim3(32*128), dim3(512), 0, stream>>>(q, k, v, wq, bq, wk, bk, wv, bv, out);
}